// Round 11
// baseline (337.285 us; speedup 1.0000x reference)
//
#include <hip/hip_runtime.h>
#include <hip/hip_bf16.h>

#define N_NODES  100000
#define N_EDGES  1600000
#define D_FEAT   128
#define N_GRAPHS 128
#define N_CLS    10
#define CAP      64
#define ZROW     100000   // dedicated all-zero fp8 row

#define NB       391      // buckets of 256 dst nodes (391*256 = 100096)
#define CAPB     4608     // staging capacity per bucket
#define CHUNK    4000     // edges per binsort block (400 * 4000 = 1.6M)
#define PCHUNK   128      // nodes per pool_partial block
#define AGG_WAVES 8192    // persistent aggregate waves (2048 blocks)
#define WPAD     136      // padded LDS row stride for Wt (breaks bank aliasing)

typedef __bf16 bf16x8 __attribute__((ext_vector_type(8)));
typedef float  f32x4  __attribute__((ext_vector_type(4)));
typedef float  f32x2  __attribute__((ext_vector_type(2)));

// ---------------- W transpose + bf16 convert (Wt[n][k]) + zero-row init ----------------
__global__ __launch_bounds__(256) void prepW(const float* __restrict__ W0,
                                             const float* __restrict__ W1,
                                             const float* __restrict__ W2,
                                             __bf16* __restrict__ wt,
                                             unsigned char* __restrict__ Hs) {
    int idx = blockIdx.x * 256 + threadIdx.x;
    if (blockIdx.x == 0 && threadIdx.x < 32)
        ((unsigned int*)(Hs + (size_t)ZROW * 128))[threadIdx.x] = 0u;
    if (idx >= 3 * 16384) return;
    int which = idx >> 14, e = idx & 16383;
    int k = e >> 7, n = e & 127;
    const float* W = (which == 0) ? W0 : ((which == 1) ? W1 : W2);
    wt[which * 16384 + n * 128 + k] = (__bf16)W[k * 128 + n];
}

// ---------------- pass 1: block-local counting sort of edges by dst bucket ----------------
__global__ __launch_bounds__(512) void binsort(const int* __restrict__ ei,
                                               int* __restrict__ gcur,
                                               int* __restrict__ staging) {
    __shared__ int hist[512];
    __shared__ int hscan[512];
    __shared__ int cur[512];
    __shared__ int gofs[512];
    __shared__ uint2 lbuf[CHUNK];   // 32 KB
    int t = threadIdx.x;
    int base = blockIdx.x * CHUNK;

    hist[t] = 0;
    __syncthreads();
    for (int i = t; i < CHUNK; i += 512)
        atomicAdd(&hist[ei[N_EDGES + base + i] >> 8], 1);
    __syncthreads();
    hscan[t] = hist[t];
    __syncthreads();
    for (int off = 1; off < 512; off <<= 1) {
        int v = (t >= off) ? hscan[t - off] : 0;
        __syncthreads();
        hscan[t] += v;
        __syncthreads();
    }
    int ex = hscan[t] - hist[t];
    cur[t] = ex;
    if (t < NB && hist[t] > 0) {
        int gb = atomicAdd(&gcur[t], hist[t]);
        gofs[t] = t * CAPB + gb - ex;
    }
    __syncthreads();
    for (int i = t; i < CHUNK; i += 512) {
        unsigned src = (unsigned)ei[base + i];
        unsigned dst = (unsigned)ei[N_EDGES + base + i];
        int p = atomicAdd(&cur[dst >> 8], 1);
        lbuf[p] = make_uint2(src, dst);
    }
    __syncthreads();
    for (int i = t; i < CHUNK; i += 512) {
        uint2 v = lbuf[i];
        int b = (int)(v.y >> 8);
        staging[gofs[b] + i] = (int)(((v.y & 255u) << 24) | v.x);
    }
}

// ---------------- pass 2: per-bucket srclist build in LDS, streamed out ----------------
// Slots pre-filled with ZROW so entries [deg, 64) are safe padding (lets the
// aggregate fetch drop its bounds cndmask). Slot 0 = self edge; lcnt starts at 1.
__global__ __launch_bounds__(256) void build_csr(const int* __restrict__ gcur,
                                                 const int* __restrict__ staging,
                                                 int* __restrict__ srclist,
                                                 int* __restrict__ cnt,
                                                 float* __restrict__ dinv) {
    __shared__ int slots[256 * CAP];   // 64 KB
    __shared__ int lcnt[256];
    int t = threadIdx.x, b = blockIdx.x;
    int4 z4 = make_int4(ZROW, ZROW, ZROW, ZROW);
    for (int j = t; j < 256 * CAP / 4; j += 256) ((int4*)slots)[j] = z4;
    lcnt[t] = 1;
    __syncthreads();
    slots[t * CAP] = b * 256 + t;      // self edge at slot 0
    __syncthreads();
    int cb = gcur[b];
    if (cb > CAPB) cb = CAPB;
    const int* st = staging + b * CAPB;
    for (int i = t; i < cb; i += 256) {
        int v = st[i];
        int ld = ((unsigned)v) >> 24;
        int s = v & 0xFFFFFF;
        int p = atomicAdd(&lcnt[ld], 1);
        if (p < CAP) slots[ld * CAP + p] = s;
    }
    __syncthreads();
    int4* d4 = (int4*)(srclist + (size_t)b * 256 * CAP);
    const int4* s4 = (const int4*)slots;
    for (int j = t; j < 256 * CAP / 4; j += 256) d4[j] = s4[j];
    int node = b * 256 + t;
    if (node < N_NODES) {
        int c = lcnt[t];
        if (c > CAP) c = CAP;
        cnt[node] = c;                       // includes self
        dinv[node] = rsqrtf((float)c);       // rsqrt(deg_true + 1)
    }
}

// ---------------- GEMM: Hs[row] = fp8(dinv[row] * (A @ W)[row]), bf16 MFMA ----------------
// Wt staged in LDS once per block; each wave computes TWO 16-row tiles sharing
// every B-fragment ds_read (MFMA:ds_read = 2:1, staging amortized 2x).
template <bool A_IS_F32>
__global__ __launch_bounds__(256) void gemm128(const void* __restrict__ Ap,
                                               const __bf16* __restrict__ Wt,
                                               const float* __restrict__ dinv,
                                               unsigned char* __restrict__ Hs) {
    __shared__ __bf16 wlds[128 * WPAD];   // ~34 KB
    int t = threadIdx.x;
    int wid = (blockIdx.x * 256 + t) >> 6;
    int lane = t & 63;
    int m = lane & 15, q = lane >> 4;
    int rowA = wid * 32 + m;
    int rowB = rowA + 16;
    bool active = wid < N_NODES / 32;    // 3125 waves exactly

    // cooperative Wt -> LDS (2048 x 16B, rows padded to WPAD elements)
    {
        const bf16x8* src = (const bf16x8*)Wt;
        for (int j = t; j < 2048; j += 256) {
            int r = j >> 4, c = (j & 15) * 8;
            *(bf16x8*)(wlds + r * WPAD + c) = src[j];
        }
    }

    // prefetch all A fragments (independent global loads) before the barrier
    bf16x8 afA[4], afB[4];
    float dvA = 0.f, dvB = 0.f;
    if (active) {
        dvA = dinv[rowA];
        dvB = dinv[rowB];
        if (A_IS_F32) {
            const float* A0 = (const float*)Ap + (size_t)rowA * 128 + q * 8;
            const float* A1 = (const float*)Ap + (size_t)rowB * 128 + q * 8;
            f32x4 va[8], vb[8];
#pragma unroll
            for (int ks = 0; ks < 4; ++ks) {
                va[2 * ks]     = *(const f32x4*)(A0 + ks * 32);
                va[2 * ks + 1] = *(const f32x4*)(A0 + ks * 32 + 4);
                vb[2 * ks]     = *(const f32x4*)(A1 + ks * 32);
                vb[2 * ks + 1] = *(const f32x4*)(A1 + ks * 32 + 4);
            }
#pragma unroll
            for (int ks = 0; ks < 4; ++ks)
#pragma unroll
                for (int j = 0; j < 4; ++j) {
                    afA[ks][j]     = (__bf16)va[2 * ks][j];
                    afA[ks][4 + j] = (__bf16)va[2 * ks + 1][j];
                    afB[ks][j]     = (__bf16)vb[2 * ks][j];
                    afB[ks][4 + j] = (__bf16)vb[2 * ks + 1][j];
                }
        } else {
            const __bf16* A0 = (const __bf16*)Ap + (size_t)rowA * 128 + q * 8;
            const __bf16* A1 = (const __bf16*)Ap + (size_t)rowB * 128 + q * 8;
#pragma unroll
            for (int ks = 0; ks < 4; ++ks) {
                afA[ks] = *(const bf16x8*)(A0 + ks * 32);
                afB[ks] = *(const bf16x8*)(A1 + ks * 32);
            }
        }
    }
    __syncthreads();
    if (!active) return;

    f32x4 accA[8] = {}, accB[8] = {};
#pragma unroll
    for (int ks = 0; ks < 4; ++ks) {
#pragma unroll
        for (int tj = 0; tj < 8; ++tj) {
            bf16x8 b = *(const bf16x8*)(wlds + (tj * 16 + m) * WPAD + ks * 32 + q * 8);
            // swapped operands: D = (W-tile)^T x X-rows -> features contiguous per lane
            accA[tj] = __builtin_amdgcn_mfma_f32_16x16x32_bf16(b, afA[ks], accA[tj], 0, 0, 0);
            accB[tj] = __builtin_amdgcn_mfma_f32_16x16x32_bf16(b, afB[ks], accB[tj], 0, 0, 0);
        }
    }

    // D layout (swapped): node = row, features tj*16 + q*4 + {0..3}
    unsigned char* rpA = Hs + (size_t)rowA * 128 + q * 4;
    unsigned char* rpB = Hs + (size_t)rowB * 128 + q * 4;
#pragma unroll
    for (int tj = 0; tj < 8; ++tj) {
        int lo = __builtin_amdgcn_cvt_pk_fp8_f32(accA[tj][0] * dvA, accA[tj][1] * dvA, 0, false);
        int w  = __builtin_amdgcn_cvt_pk_fp8_f32(accA[tj][2] * dvA, accA[tj][3] * dvA, lo, true);
        *(unsigned int*)(rpA + tj * 16) = (unsigned int)w;
        int lo2 = __builtin_amdgcn_cvt_pk_fp8_f32(accB[tj][0] * dvB, accB[tj][1] * dvB, 0, false);
        int w2  = __builtin_amdgcn_cvt_pk_fp8_f32(accB[tj][2] * dvB, accB[tj][3] * dvB, lo2, true);
        *(unsigned int*)(rpB + tj * 16) = (unsigned int)w2;
    }
}

// ---------------- aggregation: register-resident src list, depth-3 gather pipeline ----------------
// ZROW-padded lists: fetch needs no bounds check, only & 63 (over-fetches are dead values).
template <bool RELU>
__global__ __launch_bounds__(256, 8) void aggregate(const unsigned char* __restrict__ Hs,
                                                    const float* __restrict__ bias,
                                                    const float* __restrict__ dinv,
                                                    const int* __restrict__ cnt,
                                                    const int* __restrict__ srclist,
                                                    __bf16* __restrict__ X) {
    int wid = (blockIdx.x * 256 + threadIdx.x) >> 6;   // 0..AGG_WAVES-1
    int lane = threadIdx.x & 63;
    int g = lane >> 4;
    int idx = lane & 15;
    unsigned rowoff = (unsigned)idx * 8;

    f32x4 bb0 = *(const f32x4*)(bias + idx * 8);
    f32x4 bb1 = *(const f32x4*)(bias + idx * 8 + 4);

    for (int node = wid; node < N_NODES; node += AGG_WAVES) {
        float di = dinv[node];
        int deg = cnt[node];                                  // includes self, in [1, CAP]
        int myS = srclist[(size_t)node * CAP + lane];         // full list in registers

        f32x2 acc[4] = {};

        auto fetch = [&](int e) -> uint2 {
            int se = __shfl(myS, (e + g) & 63);
            unsigned off = ((unsigned)se << 7) + rowoff;
            return *(const uint2*)(Hs + off);
        };

        uint2 v0 = fetch(0);
        uint2 v1 = fetch(4);
        uint2 v2 = fetch(8);
        for (int e = 0; e < deg; e += 4) {
            uint2 vn = fetch(e + 12);
            acc[0] += __builtin_amdgcn_cvt_pk_f32_fp8(v0.x, false);
            acc[1] += __builtin_amdgcn_cvt_pk_f32_fp8(v0.x, true);
            acc[2] += __builtin_amdgcn_cvt_pk_f32_fp8(v0.y, false);
            acc[3] += __builtin_amdgcn_cvt_pk_f32_fp8(v0.y, true);
            v0 = v1; v1 = v2; v2 = vn;
        }

        float a[8];
#pragma unroll
        for (int j = 0; j < 4; ++j) { a[2 * j] = acc[j][0]; a[2 * j + 1] = acc[j][1]; }
#pragma unroll
        for (int j = 0; j < 8; ++j) {
            a[j] += __shfl_xor(a[j], 16);
            a[j] += __shfl_xor(a[j], 32);
        }

        bf16x8 o;
#pragma unroll
        for (int j = 0; j < 8; ++j) {
            float bj = (j < 4) ? bb0[j] : bb1[j - 4];
            float t = di * a[j] + bj;
            if (RELU) t = fmaxf(t, 0.f);
            o[j] = (__bf16)t;
        }
        if (g == 0) *(bf16x8*)(X + (size_t)node * 128 + idx * 8) = o;
    }
}

// ---------------- pooling stage 1: per-chunk fp32 partial sums, atomic flush ----------------
__global__ __launch_bounds__(256) void pool_partial(const __bf16* __restrict__ X,
                                                    const int* __restrict__ batch,
                                                    float* __restrict__ sums) {
    int t = threadIdx.x;
    int d = t & 127, half = t >> 7;
    int start = blockIdx.x * PCHUNK;
    int end = start + PCHUNK;
    if (end > N_NODES) end = N_NODES;
    float acc = 0.f;
    int curg = -1;
    for (int i = start + half; i < end; i += 2) {
        int g = batch[i];
        if (g != curg) {
            if (curg >= 0) atomicAdd(&sums[curg * 128 + d], acc);
            acc = 0.f;
            curg = g;
        }
        acc += (float)X[(size_t)i * 128 + d];
    }
    if (curg >= 0) atomicAdd(&sums[curg * 128 + d], acc);
}

// ---------------- pooling stage 2: divide, linear, softmax ----------------
__global__ __launch_bounds__(64) void pool_final(const float* __restrict__ sums,
                                                 const int* __restrict__ batch,
                                                 const float* __restrict__ linW,
                                                 const float* __restrict__ linb,
                                                 float* __restrict__ out) {
    int g = blockIdx.x, lane = threadIdx.x;
    int bnd[2];
#pragma unroll
    for (int k = 0; k < 2; ++k) {
        int target = g + k;
        int lo = 0, hi = N_NODES;
        while (lo < hi) {
            int mid = (lo + hi) >> 1;
            if (batch[mid] < target) lo = mid + 1; else hi = mid;
        }
        bnd[k] = lo;
    }
    float c = fmaxf((float)(bnd[1] - bnd[0]), 1.f);
    float p0 = sums[g * 128 + lane] / c;
    float p1 = sums[g * 128 + 64 + lane] / c;

    float lg[N_CLS];
#pragma unroll
    for (int cc = 0; cc < N_CLS; ++cc) {
        float v = p0 * linW[lane * N_CLS + cc] + p1 * linW[(lane + 64) * N_CLS + cc];
#pragma unroll
        for (int off = 1; off < 64; off <<= 1) v += __shfl_xor(v, off);
        lg[cc] = v + linb[cc];
    }
    float mx = -1e30f;
#pragma unroll
    for (int cc = 0; cc < N_CLS; ++cc) mx = fmaxf(mx, lg[cc]);
    float ssum = 0.f;
#pragma unroll
    for (int cc = 0; cc < N_CLS; ++cc) { lg[cc] = __expf(lg[cc] - mx); ssum += lg[cc]; }
    if (lane < N_CLS) out[g * N_CLS + lane] = lg[lane] / ssum;
}

extern "C" void kernel_launch(void* const* d_in, const int* in_sizes, int n_in,
                              void* d_out, int out_size, void* d_ws, size_t ws_size,
                              hipStream_t stream) {
    const float* x     = (const float*)d_in[0];
    const int*   ei    = (const int*)d_in[1];
    const int*   batch = (const int*)d_in[2];
    const float* W0    = (const float*)d_in[3];
    const float* b0    = (const float*)d_in[4];
    const float* W1    = (const float*)d_in[5];
    const float* b1    = (const float*)d_in[6];
    const float* W2    = (const float*)d_in[7];
    const float* b2    = (const float*)d_in[8];
    const float* linW  = (const float*)d_in[9];
    const float* linb  = (const float*)d_in[10];

    char* ws = (char*)d_ws;
    int*    gcur    = (int*)(ws + 0);             // 2048 B
    float*  sums    = (float*)(ws + 2048);        // 65536 B
    float*  dinv    = (float*)(ws + 67584);       // 400000 B
    int*    cnt     = (int*)(ws + 467584);        // 400000 B
    __bf16* wt      = (__bf16*)(ws + 867584);     // 98304 B
    int*    srclist = (int*)(ws + 965888);        // 25624576 B
    unsigned char* Hs = (unsigned char*)(ws + 26590464); // 12.8 MB fp8 (+ zero row)
    int*    staging = (int*)(ws + 26590464);      // 7.2 MB, aliases Hs (dead before gemm)
    __bf16* xbuf    = (__bf16*)(ws + 52190464);   // 25.6 MB

    hipMemsetAsync(ws, 0, 67584, stream);         // gcur + sums

    prepW<<<192, 256, 0, stream>>>(W0, W1, W2, wt, Hs);   // also zeroes Hs[ZROW]
    binsort<<<N_EDGES / CHUNK, 512, 0, stream>>>(ei, gcur, staging);
    build_csr<<<NB, 256, 0, stream>>>(gcur, staging, srclist, cnt, dinv);

    // Layer 0  (3125 waves of 32 rows -> 782 blocks)
    gemm128<true><<<782, 256, 0, stream>>>(x, wt, dinv, Hs);
    aggregate<true><<<AGG_WAVES / 4, 256, 0, stream>>>(Hs, b0, dinv, cnt, srclist, xbuf);
    // Layer 1
    gemm128<false><<<782, 256, 0, stream>>>(xbuf, wt + 16384, dinv, Hs);
    aggregate<true><<<AGG_WAVES / 4, 256, 0, stream>>>(Hs, b1, dinv, cnt, srclist, xbuf);
    // Layer 2 (no relu)
    gemm128<false><<<782, 256, 0, stream>>>(xbuf, wt + 32768, dinv, Hs);
    aggregate<false><<<AGG_WAVES / 4, 256, 0, stream>>>(Hs, b2, dinv, cnt, srclist, xbuf);

    pool_partial<<<(N_NODES + PCHUNK - 1) / PCHUNK, 256, 0, stream>>>(xbuf, batch, sums);
    pool_final<<<N_GRAPHS, 64, 0, stream>>>(sums, batch, linW, linb, (float*)d_out);
}